// Round 1
// baseline (113.141 us; speedup 1.0000x reference)
//
#include <hip/hip_runtime.h>
#include <math.h>

#define BB 4
#define RR 1024
#define NN 100

// Exact rotated-rect BEV intersection + 3D IoU, mirroring the reference math.
__device__ __forceinline__ float iou3d_pair(const float a[7], const float b[7]) {
    // z overlap (reference clips to 0; 0 height overlap -> inter = 0 -> iou = 0)
    float oh = fminf(a[2] + a[5] * 0.5f, b[2] + b[5] * 0.5f)
             - fmaxf(a[2] - a[5] * 0.5f, b[2] - b[5] * 0.5f);
    // bounding-circle fast reject in BEV (relaxation: circles contain rects,
    // so reject => rects disjoint => inter_bev = 0 => iou exactly 0, matching ref)
    float dxc = a[0] - b[0], dyc = a[1] - b[1];
    float ra = 0.5f * sqrtf(a[3] * a[3] + a[4] * a[4]);
    float rb = 0.5f * sqrtf(b[3] * b[3] + b[4] * b[4]);
    float rr = ra + rb;
    if (oh <= 0.0f || dxc * dxc + dyc * dyc > rr * rr) return 0.0f;

    float ac = cosf(a[6]), as_ = sinf(a[6]);
    float bc = cosf(b[6]), bs_ = sinf(b[6]);

    const float lxs[4] = {0.5f, -0.5f, -0.5f, 0.5f};
    const float lys[4] = {0.5f,  0.5f, -0.5f, -0.5f};
    float cax[4], cay[4], cbx[4], cby[4];
#pragma unroll
    for (int i = 0; i < 4; i++) {
        float lx = lxs[i] * a[3], ly = lys[i] * a[4];
        cax[i] = a[0] + lx * ac - ly * as_;
        cay[i] = a[1] + lx * as_ + ly * ac;
        float mx = lxs[i] * b[3], my = lys[i] * b[4];
        cbx[i] = b[0] + mx * bc - my * bs_;
        cby[i] = b[1] + mx * bs_ + my * bc;
    }

    float px[24], py[24];
    unsigned valid = 0u;

    // corners of A inside B
#pragma unroll
    for (int i = 0; i < 4; i++) {
        px[i] = cax[i]; py[i] = cay[i];
        float qx = cax[i] - b[0], qy = cay[i] - b[1];
        float lx = qx * bc + qy * bs_;
        float ly = -qx * bs_ + qy * bc;
        if (fabsf(lx) <= b[3] * 0.5f + 1e-5f && fabsf(ly) <= b[4] * 0.5f + 1e-5f)
            valid |= 1u << i;
    }
    // corners of B inside A
#pragma unroll
    for (int i = 0; i < 4; i++) {
        px[4 + i] = cbx[i]; py[4 + i] = cby[i];
        float qx = cbx[i] - a[0], qy = cby[i] - a[1];
        float lx = qx * ac + qy * as_;
        float ly = -qx * as_ + qy * ac;
        if (fabsf(lx) <= a[3] * 0.5f + 1e-5f && fabsf(ly) <= a[4] * 0.5f + 1e-5f)
            valid |= 1u << (4 + i);
    }
    // edge-edge intersections (i over A edges, j over B edges; slot 8 + i*4 + j)
#pragma unroll
    for (int i = 0; i < 4; i++) {
        float a1x = cax[i], a1y = cay[i];
        float d1x = cax[(i + 1) & 3] - a1x, d1y = cay[(i + 1) & 3] - a1y;
#pragma unroll
        for (int j = 0; j < 4; j++) {
            float b1x = cbx[j], b1y = cby[j];
            float d2x = cbx[(j + 1) & 3] - b1x, d2y = cby[(j + 1) & 3] - b1y;
            float denom = d1x * d2y - d1y * d2x;
            float fx = b1x - a1x, fy = b1y - a1y;
            float safe = (fabsf(denom) > 1e-8f) ? denom : 1e-8f;
            float t = (fx * d2y - fy * d2x) / safe;
            float u = (fx * d1y - fy * d1x) / safe;
            int k = 8 + i * 4 + j;
            px[k] = a1x + t * d1x;
            py[k] = a1y + t * d1y;
            if (fabsf(denom) > 1e-8f && t >= 0.0f && t <= 1.0f && u >= 0.0f && u <= 1.0f)
                valid |= 1u << k;
        }
    }

    int nv = __popc(valid);
    float inter_bev = 0.0f;
    if (nv >= 3) {
        float sx = 0.0f, sy = 0.0f;
#pragma unroll
        for (int k = 0; k < 24; k++) {
            if ((valid >> k) & 1u) { sx += px[k]; sy += py[k]; }
        }
        float cx = sx / (float)nv, cy = sy / (float)nv;

        float ang[24];
#pragma unroll
        for (int k = 0; k < 24; k++) {
            ang[k] = ((valid >> k) & 1u) ? atan2f(py[k] - cy, px[k] - cx) : 1e9f;
        }

        // shoelace over valid vertices in (angle, index)-sorted cyclic order,
        // via successor search (identical to stable argsort + pad-with-first).
        float area2 = 0.0f;
#pragma unroll
        for (int k = 0; k < 24; k++) {
            if (!((valid >> k) & 1u)) continue;
            float ak = ang[k];
            float sAng = 1e30f, sxp = 0.0f, syp = 0.0f; int sIdx = 64; bool found = false;
            float gAng = 1e30f, gxp = 0.0f, gyp = 0.0f; int gIdx = 64;
#pragma unroll
            for (int j = 0; j < 24; j++) {
                if (!((valid >> j) & 1u)) continue;
                float aj = ang[j];
                bool greater = (aj > ak) || (aj == ak && j > k);
                if (greater && ((aj < sAng) || (aj == sAng && j < sIdx))) {
                    sAng = aj; sIdx = j; sxp = px[j]; syp = py[j]; found = true;
                }
                if ((aj < gAng) || (aj == gAng && j < gIdx)) {
                    gAng = aj; gIdx = j; gxp = px[j]; gyp = py[j];
                }
            }
            float qx = found ? sxp : gxp;
            float qy = found ? syp : gyp;
            area2 += px[k] * qy - qx * py[k];
        }
        inter_bev = 0.5f * fabsf(area2);
    }

    float inter = inter_bev * oh;  // oh > 0 here
    float va = a[3] * a[4] * a[5];
    float vb = b[3] * b[4] * b[5];
    float den = fmaxf(va + vb - inter, 1e-6f);
    return inter / den;
}

__global__ __launch_bounds__(256) void sampling_target_kernel(
    const float* __restrict__ rois,   // (B,R,7)
    const int*   __restrict__ labels, // (B,R)
    const float* __restrict__ gts,    // (B,N,8)
    float*       __restrict__ out)    // concat: rois(B,R,7) | gt_of_rois(B,R,8) | max(B,R) | labels(B,R) | mask(B,R)
{
    int wave = (int)((blockIdx.x * blockDim.x + threadIdx.x) >> 6);  // one wave per ROI
    int lane = threadIdx.x & 63;
    if (wave >= BB * RR) return;
    int b = wave >> 10;  // RR = 1024

    float a[7];
    const float* ap = rois + wave * 7;
#pragma unroll
    for (int k = 0; k < 7; k++) a[k] = ap[k];

    const float* gb = gts + b * NN * 8;

    float best = -1.0f;
    int besti = 0;
    for (int n = lane; n < NN; n += 64) {
        float bx[7];
        const float* bp = gb + n * 8;
#pragma unroll
        for (int k = 0; k < 7; k++) bx[k] = bp[k];
        float v = iou3d_pair(a, bx);
        if (v > best) { best = v; besti = n; }  // strict > keeps earliest n on ties
    }

    // 64-lane butterfly reduce: max value, smallest index on exact ties
#pragma unroll
    for (int off = 32; off > 0; off >>= 1) {
        float ov = __shfl_xor(best, off, 64);
        int   oi = __shfl_xor(besti, off, 64);
        if (ov > best || (ov == best && oi < besti)) { best = ov; besti = oi; }
    }

    if (lane == 0) {
        float* out_rois = out;                            // B*R*7
        float* out_gor  = out + BB * RR * 7;              // B*R*8
        float* out_max  = out_gor + BB * RR * 8;          // B*R
        float* out_lab  = out_max + BB * RR;              // B*R
        float* out_msk  = out_lab + BB * RR;              // B*R
#pragma unroll
        for (int k = 0; k < 7; k++) out_rois[wave * 7 + k] = a[k];
        const float* gp = gb + besti * 8;
#pragma unroll
        for (int k = 0; k < 8; k++) out_gor[wave * 8 + k] = gp[k];
        out_max[wave] = best;
        out_lab[wave] = (float)labels[wave];
        out_msk[wave] = (best > 0.55f) ? 1.0f : 0.0f;
    }
}

extern "C" void kernel_launch(void* const* d_in, const int* in_sizes, int n_in,
                              void* d_out, int out_size, void* d_ws, size_t ws_size,
                              hipStream_t stream) {
    const float* rois   = (const float*)d_in[0];  // (4,1024,7) f32
    const int*   labels = (const int*)d_in[1];    // (4,1024) i32
    const float* gts    = (const float*)d_in[2];  // (4,100,8) f32
    float* out = (float*)d_out;

    // one wave (64 lanes) per ROI: 4096 waves -> 1024 blocks of 256 threads
    dim3 grid(1024), block(256);
    hipLaunchKernelGGL(sampling_target_kernel, grid, block, 0, stream,
                       rois, labels, gts, out);
}